// Round 4
// baseline (318.373 us; speedup 1.0000x reference)
//
#include <hip/hip_runtime.h>
#include <cmath>

#define XR_RT   32   // r-rows per block in xred kernel
#define XR_BC   32   // b-values per block in xred kernel
#define OGROUP  8    // o-rows per block in main kernel
#define BCHUNK  16   // b-values per block iteration chunk
#define NSLOT   (OGROUP * 128)   // 1024 slots per o-region

typedef float nfloat4 __attribute__((ext_vector_type(4)));  // native vec for nontemporal builtins

// ---------------- Kernel 1: x_red[b,r] = sum_i x[b,i] * mask[r,i] ----------------
__global__ __launch_bounds__(256) void xred_kernel(const float* __restrict__ x,
                                                   const float* __restrict__ mask,
                                                   float* __restrict__ xred) {
    __shared__ float ms[XR_RT][129];
    __shared__ float xs[128][40];
    const int tid = threadIdx.x;
    const int r0  = blockIdx.x * XR_RT;
    const int b0  = blockIdx.y * XR_BC;

    const float4* m4 = (const float4*)(mask + (size_t)r0 * 128);
    for (int k = tid; k < XR_RT * 32; k += 256) {
        float4 v = m4[k];
        int row = k >> 5;
        int col = (k & 31) * 4;
        ms[row][col]     = v.x;
        ms[row][col + 1] = v.y;
        ms[row][col + 2] = v.z;
        ms[row][col + 3] = v.w;
    }
    for (int k = tid; k < XR_BC * 128; k += 256) {
        int b = k >> 7, i = k & 127;
        xs[i][b] = x[(size_t)(b0 + b) * 128 + i];
    }
    __syncthreads();

    const int r = tid & 31;
    const int g = tid >> 5;
    float acc[4] = {0.f, 0.f, 0.f, 0.f};
    for (int i = 0; i < 128; ++i) {
        const float  m  = ms[r][i];
        const float4 xa = *(const float4*)&xs[i][4 * g];
        acc[0] += m * xa.x; acc[1] += m * xa.y; acc[2] += m * xa.z; acc[3] += m * xa.w;
    }
    #pragma unroll
    for (int j = 0; j < 4; ++j)
        xred[(size_t)(b0 + 4 * g + j) * 128 + (r0 + r)] = acc[j];
}

// ---------------- Kernel 2: class-sorted activation kernel ----------------
// Each block owns an o-region of 8 rows (1024 slots). Prologue sorts slot indices by
// activation class (LDS histogram + scan + atomic placement) so that threads process
// class-contiguous slots: interior waves execute exactly ONE activation branch instead
// of computing all ten and selecting (issue-bound fix). Results are scattered into a
// double-buffered LDS tile and re-read linearly so postacts stores remain coalesced
// float4 and the y xor-tree reduction is unchanged.
__global__ __launch_bounds__(256) void kan_main(const float* __restrict__ xred,
                                                const float4* __restrict__ affine,
                                                const int* __restrict__ fun_ids,
                                                float* __restrict__ y,
                                                float4* __restrict__ post4) {
    __shared__ int hist[8];
    __shared__ int base[8];
    __shared__ unsigned short sorted[NSLOT];   // 2 KB: slot | (id<<10)
    __shared__ float pbuf[2][NSLOT];           // 8 KB double buffer

    const int tid = threadIdx.x;
    const int reg = blockIdx.x;                // o = reg*8 + (tid>>5)
    const int b0  = blockIdx.y * BCHUNK;
    const int oo  = tid >> 5;
    const int il  = tid & 31;
    const int o   = reg * OGROUP + oo;

    // ---- prologue: classify + sort slots by class ----
    if (tid < 8) hist[tid] = 0;
    __syncthreads();

    const int4 fid = ((const int4*)(fun_ids + (size_t)reg * NSLOT))[tid];  // slots 4t..4t+3
    const int myid[4] = {fid.x, fid.y, fid.z, fid.w};
    int mycls[4];
    #pragma unroll
    for (int j = 0; j < 4; ++j) {
        const int id = myid[j];
        mycls[j] = (id == 3) ? 1 : (id == 4 || id == 5) ? 2
                 : (id == 6 || id == 9) ? 3 : (id == 8) ? 4 : 0;
        atomicAdd(&hist[mycls[j]], 1);
    }
    __syncthreads();
    if (tid == 0) {
        int acc = 0;
        #pragma unroll
        for (int c = 0; c < 5; ++c) { base[c] = acc; acc += hist[c]; }
    }
    __syncthreads();
    #pragma unroll
    for (int j = 0; j < 4; ++j) {
        const int pos = atomicAdd(&base[mycls[j]], 1);
        sorted[pos] = (unsigned short)((4 * tid + j) | (myid[j] << 10));
    }
    __syncthreads();

    // ---- hoist per-element state for the thread's 4 SORTED slots ----
    int   slt[4], ii[4], cls[4];
    float Aa[4], Ab[4], Ac[4], Ad[4];
    bool  m1[4], m2[4], m7[4];
    float k1[4], k2[4], An[4], Bn[4];
    #pragma unroll
    for (int j = 0; j < 4; ++j) {
        const int v  = sorted[4 * tid + j];
        const int sl = v & 1023;
        const int id = v >> 10;
        slt[j] = sl;
        ii[j]  = sl & 127;
        cls[j] = (id == 3) ? 1 : (id == 4 || id == 5) ? 2
               : (id == 6 || id == 9) ? 3 : (id == 8) ? 4 : 0;
        const float4 A = affine[(size_t)reg * NSLOT + sl];
        Aa[j] = A.x; Ab[j] = A.y; Ac[j] = A.z; Ad[j] = A.w;
        m1[j] = (id == 1); m2[j] = (id == 2); m7[j] = (id == 7);
        float k1v = 0.f, k2v = 0.f, Anv = 0.f, Bnv = 1.f;
        if      (id == 4) { k1v = -2.f; Anv = 1.f; Bnv = -1.f; }  // tanh
        else if (id == 5) { k1v = -1.f; Anv = 1.f; Bnv =  0.f; }  // sigmoid
        else if (id == 6) { k2v = -1.f; }                         // exp(-z^2)
        else if (id == 9) { k1v =  1.f; }                         // exp(z)
        k1[j] = k1v; k2[j] = k2v; An[j] = Anv; Bn[j] = Bnv;
    }

    // ---- b-loop ----
    float xg[4];
    #pragma unroll
    for (int j = 0; j < 4; ++j) xg[j] = xred[(size_t)b0 * 128 + ii[j]];

    int par = 0;
    for (int bb = 0; bb < BCHUNK; ++bb) {
        const int b = b0 + bb;
        // prefetch next b's gathered xred values (L2-hot 512B row)
        float xn[4] = {xg[0], xg[1], xg[2], xg[3]};
        if (bb + 1 < BCHUNK) {
            #pragma unroll
            for (int j = 0; j < 4; ++j) xn[j] = xred[(size_t)(b + 1) * 128 + ii[j]];
        }

        float p[4];
        #pragma unroll
        for (int j = 0; j < 4; ++j) {
            const float z = fmaf(Aa[j], xg[j], Ab[j]);
            float pv;
            const int cj = cls[j];
            if (cj == 0) {            // poly: z, z^2, z^3, |z|
                const float zz = z * z;
                pv = m1[j] ? zz : z;
                pv = m2[j] ? zz * z : pv;
                pv = m7[j] ? fabsf(z) : pv;
            } else if (cj == 1) {     // sin
                pv = __sinf(z);
            } else if (cj == 2) {     // tanh / sigmoid: (An + Bn*e)/(1+e), e = exp(k1*z)
                const float e = __expf(fminf(k1[j] * z, 80.f));
                pv = fmaf(Bn[j], e, An[j]) * __builtin_amdgcn_rcpf(1.f + e);
            } else if (cj == 3) {     // exp(z) / exp(-z^2)
                const float arg = fminf(fmaf(k2[j], z * z, k1[j] * z), 80.f);
                pv = __expf(arg);
            } else {                  // atan, 5-term minimax
                const float az  = fabsf(z);
                const bool  big = az > 1.0f;
                const float t   = big ? __builtin_amdgcn_rcpf(az) : az;
                const float t2  = t * t;
                float q = fmaf(t2, -0.01172120f, 0.05265332f);
                q = fmaf(t2, q, -0.11643287f);
                q = fmaf(t2, q,  0.19354346f);
                q = fmaf(t2, q, -0.33262347f);
                q = fmaf(t2, q,  0.99997726f);
                q = t * q;
                q = big ? 1.57079632679f - q : q;
                pv = copysignf(q, z);
            }
            p[j] = fmaf(Ac[j], pv, Ad[j]);
        }

        // scatter to LDS (random banks, ~2-way avg), then linear coalesced read-back
        #pragma unroll
        for (int j = 0; j < 4; ++j) pbuf[par][slt[j]] = p[j];
        __syncthreads();

        const float4 q = *(const float4*)&pbuf[par][4 * tid];
        nfloat4 outv = {q.x, q.y, q.z, q.w};
        __builtin_nontemporal_store(outv,
            reinterpret_cast<nfloat4*>(&post4[((size_t)b * 128 + o) * 32 + il]));

        float s = (q.x + q.y) + (q.z + q.w);
        s += __shfl_xor(s, 1, 64);
        s += __shfl_xor(s, 2, 64);
        s += __shfl_xor(s, 4, 64);
        s += __shfl_xor(s, 8, 64);
        s += __shfl_xor(s, 16, 64);
        if (il == 0) __builtin_nontemporal_store(s, &y[(size_t)b * 128 + o]);

        par ^= 1;
        #pragma unroll
        for (int j = 0; j < 4; ++j) xg[j] = xn[j];
        // no second barrier needed: buffer par is only rewritten after the next
        // iteration's barrier, which all waves reach only after finishing this read
    }
}

extern "C" void kernel_launch(void* const* d_in, const int* in_sizes, int n_in,
                              void* d_out, int out_size, void* d_ws, size_t ws_size,
                              hipStream_t stream) {
    const float* x       = (const float*)d_in[0];   // (batch, 128)
    const float* affine  = (const float*)d_in[1];   // (128, 128, 4)
    const float* mask    = (const float*)d_in[2];   // (128, 128)
    const int*   fun_ids = (const int*)d_in[3];     // (128, 128)

    const int batch = in_sizes[0] / 128;            // 4096

    float* xred     = (float*)d_ws;                 // batch*128 floats (2 MB)
    float* y        = (float*)d_out;                // batch*128
    float* postacts = y + (size_t)batch * 128;      // batch*128*128

    xred_kernel<<<dim3(128 / XR_RT, batch / XR_BC), dim3(256), 0, stream>>>(x, mask, xred);

    kan_main<<<dim3(128 / OGROUP, batch / BCHUNK), dim3(256), 0, stream>>>(
        xred, (const float4*)affine, fun_ids, y, (float4*)postacts);
}

// Round 5
// 310.850 us; speedup vs baseline: 1.0242x; 1.0242x over previous
//
#include <hip/hip_runtime.h>
#include <cmath>

#define XR_RT   32   // r-rows per block in xred kernel
#define XR_BC   32   // b-values per block in xred kernel
#define OGROUP  8    // o-rows per block in main kernel
#define BCHUNK  32   // b-values per block (amortizes prologue)
#define YB      4    // y-reduction batch: 4 independent xor-trees

// ---------------- Kernel 1: x_red[b,r] = sum_i x[b,i] * mask[r,i] ----------------
__global__ __launch_bounds__(256) void xred_kernel(const float* __restrict__ x,
                                                   const float* __restrict__ mask,
                                                   float* __restrict__ xred) {
    __shared__ float ms[XR_RT][129];
    __shared__ float xs[128][40];
    const int tid = threadIdx.x;
    const int r0  = blockIdx.x * XR_RT;
    const int b0  = blockIdx.y * XR_BC;

    const float4* m4 = (const float4*)(mask + (size_t)r0 * 128);
    for (int k = tid; k < XR_RT * 32; k += 256) {
        float4 v = m4[k];
        int row = k >> 5;
        int col = (k & 31) * 4;
        ms[row][col]     = v.x;
        ms[row][col + 1] = v.y;
        ms[row][col + 2] = v.z;
        ms[row][col + 3] = v.w;
    }
    for (int k = tid; k < XR_BC * 128; k += 256) {
        int b = k >> 7, i = k & 127;
        xs[i][b] = x[(size_t)(b0 + b) * 128 + i];
    }
    __syncthreads();

    const int r = tid & 31;
    const int g = tid >> 5;
    float acc[4] = {0.f, 0.f, 0.f, 0.f};
    for (int i = 0; i < 128; ++i) {
        const float  m  = ms[r][i];
        const float4 xa = *(const float4*)&xs[i][4 * g];
        acc[0] += m * xa.x; acc[1] += m * xa.y; acc[2] += m * xa.z; acc[3] += m * xa.w;
    }
    #pragma unroll
    for (int j = 0; j < 4; ++j)
        xred[(size_t)(b0 + 4 * g + j) * 128 + (r0 + r)] = acc[j];
}

// ---------------- Kernel 2: z, postacts, y ----------------
// Thread owns an i-quad of one o-row (coalesced float4 stores: wave = 1 KB contiguous).
// fun_id state hoisted to registers (b-invariant). Latency plan: simple b-loop (no
// manual prefetch), but the y xor-tree reduction is BATCHED over YB=4 b-values so the
// 5-step ds_swizzle chains run as 8 independent chains (latency overlapped) instead of
// one serial chain per iteration.
__global__ __launch_bounds__(256) void kan_main(const float4* __restrict__ xred4,
                                                const float4* __restrict__ affine,
                                                const int* __restrict__ fun_ids,
                                                float* __restrict__ y,
                                                float4* __restrict__ post4) {
    const int tid = threadIdx.x;
    const int oo  = tid >> 5;                 // 0..7 : o-row within block
    const int il  = tid & 31;                 // i-quad index (i = 4*il .. 4*il+3)
    const int o   = blockIdx.x * OGROUP + oo;

    // ---- hoist per-element affine + fun_id-derived state (b-invariant) ----
    float4 A[4]; int f[4];
    #pragma unroll
    for (int j = 0; j < 4; ++j) {
        A[j] = affine[(size_t)o * 128 + il * 4 + j];
        f[j] = fun_ids[(size_t)o * 128 + il * 4 + j];
    }

    bool m1[4], m2[4], m3[4], m7[4], m8[4], me[4];
    float k1[4], k2[4], An[4], Bn[4], Dd[4];
    #pragma unroll
    for (int j = 0; j < 4; ++j) {
        const int fj = f[j];
        m1[j] = (fj == 1); m2[j] = (fj == 2); m3[j] = (fj == 3);
        m7[j] = (fj == 7); m8[j] = (fj == 8);
        me[j] = (fj >= 4 && fj <= 6) || (fj == 9);
        float k1v = 0.f, k2v = 0.f, Anv = 0.f, Bnv = 1.f, Ddv = 0.f;
        if      (fj == 4) { k1v = -2.f; Anv = 1.f; Bnv = -1.f; Ddv = 1.f; }  // tanh
        else if (fj == 5) { k1v = -1.f; Anv = 1.f; Bnv =  0.f; Ddv = 1.f; }  // sigmoid
        else if (fj == 6) { k2v = -1.f; }                                    // exp(-z^2)
        else if (fj == 9) { k1v =  1.f; }                                    // exp(z)
        k1[j] = k1v; k2[j] = k2v; An[j] = Anv; Bn[j] = Bnv; Dd[j] = Ddv;
    }

    const int b0 = blockIdx.y * BCHUNK;

    for (int q = 0; q < BCHUNK / YB; ++q) {
        float sv[YB];

        #pragma unroll
        for (int k = 0; k < YB; ++k) {
            const int b = b0 + q * YB + k;
            const float4 xr = xred4[(size_t)b * 32 + il];
            const float xv[4] = {xr.x, xr.y, xr.z, xr.w};

            float p[4];
            #pragma unroll
            for (int j = 0; j < 4; ++j) {
                const float z  = fmaf(A[j].x, xv[j], A[j].y);
                const float zz = z * z;
                float pv = m1[j] ? zz : z;
                pv = m2[j] ? zz * z : pv;
                pv = m7[j] ? fabsf(z) : pv;
                const float s = __sinf(z);
                pv = m3[j] ? s : pv;
                const float arg = fminf(fmaf(k2[j], zz, k1[j] * z), 80.f);
                const float e   = __expf(arg);
                const float num = fmaf(Bn[j], e, An[j]);
                const float den = fmaf(Dd[j], e, 1.0f);
                const float r   = num * __builtin_amdgcn_rcpf(den);
                pv = me[j] ? r : pv;
                // atan: 5-term minimax (abs err ~2e-7)
                const float az  = fabsf(z);
                const bool  big = az > 1.0f;
                const float t   = big ? __builtin_amdgcn_rcpf(az) : az;
                const float t2  = t * t;
                float qq = fmaf(t2, -0.01172120f, 0.05265332f);
                qq = fmaf(t2, qq, -0.11643287f);
                qq = fmaf(t2, qq,  0.19354346f);
                qq = fmaf(t2, qq, -0.33262347f);
                qq = fmaf(t2, qq,  0.99997726f);
                qq = t * qq;
                qq = big ? 1.57079632679f - qq : qq;
                const float at = copysignf(qq, z);
                pv = m8[j] ? at : pv;
                p[j] = fmaf(A[j].z, pv, A[j].w);
            }

            post4[((size_t)b * 128 + o) * 32 + il] = make_float4(p[0], p[1], p[2], p[3]);
            sv[k] = (p[0] + p[1]) + (p[2] + p[3]);
        }

        // 4 independent 5-step xor-trees back-to-back: swizzle latency overlapped
        #pragma unroll
        for (int k = 0; k < YB; ++k) {
            float s = sv[k];
            s += __shfl_xor(s, 1, 64);
            s += __shfl_xor(s, 2, 64);
            s += __shfl_xor(s, 4, 64);
            s += __shfl_xor(s, 8, 64);
            s += __shfl_xor(s, 16, 64);
            sv[k] = s;
        }
        if (il == 0) {
            #pragma unroll
            for (int k = 0; k < YB; ++k)
                y[(size_t)(b0 + q * YB + k) * 128 + o] = sv[k];
        }
    }
}

extern "C" void kernel_launch(void* const* d_in, const int* in_sizes, int n_in,
                              void* d_out, int out_size, void* d_ws, size_t ws_size,
                              hipStream_t stream) {
    const float* x       = (const float*)d_in[0];   // (batch, 128)
    const float* affine  = (const float*)d_in[1];   // (128, 128, 4)
    const float* mask    = (const float*)d_in[2];   // (128, 128)
    const int*   fun_ids = (const int*)d_in[3];     // (128, 128)

    const int batch = in_sizes[0] / 128;            // 4096

    float* xred     = (float*)d_ws;                 // batch*128 floats (2 MB)
    float* y        = (float*)d_out;                // batch*128
    float* postacts = y + (size_t)batch * 128;      // batch*128*128

    xred_kernel<<<dim3(128 / XR_RT, batch / XR_BC), dim3(256), 0, stream>>>(x, mask, xred);

    kan_main<<<dim3(128 / OGROUP, batch / BCHUNK), dim3(256), 0, stream>>>(
        (const float4*)xred, (const float4*)affine, fun_ids, y, (float4*)postacts);
}

// Round 6
// 304.216 us; speedup vs baseline: 1.0465x; 1.0218x over previous
//
#include <hip/hip_runtime.h>
#include <cmath>

#define XR_RT   32   // r-rows per block in xred kernel
#define XR_BC   32   // b-values per block in xred kernel
#define OGROUP  8    // o-rows per block in main kernel
#define BCHUNK  16   // b-values per block in main kernel

// ---------------- Kernel 1: x_red[b,r] = sum_i x[b,i] * mask[r,i] ----------------
__global__ __launch_bounds__(256) void xred_kernel(const float* __restrict__ x,
                                                   const float* __restrict__ mask,
                                                   float* __restrict__ xred) {
    __shared__ float ms[XR_RT][129];
    __shared__ float xs[128][40];
    const int tid = threadIdx.x;
    const int r0  = blockIdx.x * XR_RT;
    const int b0  = blockIdx.y * XR_BC;

    const float4* m4 = (const float4*)(mask + (size_t)r0 * 128);
    for (int k = tid; k < XR_RT * 32; k += 256) {
        float4 v = m4[k];
        int row = k >> 5;
        int col = (k & 31) * 4;
        ms[row][col]     = v.x;
        ms[row][col + 1] = v.y;
        ms[row][col + 2] = v.z;
        ms[row][col + 3] = v.w;
    }
    for (int k = tid; k < XR_BC * 128; k += 256) {
        int b = k >> 7, i = k & 127;
        xs[i][b] = x[(size_t)(b0 + b) * 128 + i];
    }
    __syncthreads();

    const int r = tid & 31;
    const int g = tid >> 5;
    float acc[4] = {0.f, 0.f, 0.f, 0.f};
    for (int i = 0; i < 128; ++i) {
        const float  m  = ms[r][i];
        const float4 xa = *(const float4*)&xs[i][4 * g];
        acc[0] += m * xa.x; acc[1] += m * xa.y; acc[2] += m * xa.z; acc[3] += m * xa.w;
    }
    #pragma unroll
    for (int j = 0; j < 4; ++j)
        xred[(size_t)(b0 + 4 * g + j) * 128 + (r0 + r)] = acc[j];
}

// ---------------- Kernel 2: z, postacts, y ----------------
// Exact best-known (R1) body. Single change this round: __launch_bounds__(256, 6)
// caps VGPR at ~85 -> 6 waves/SIMD (24 waves/CU) instead of est. 3-4. Theory: the
// residual ~60% stall is store-retire vmcnt waits + trans latency exposed by low
// occupancy; more co-resident waves cover it. All other levers proven null (R1-R5).
__global__ __launch_bounds__(256, 6) void kan_main(const float4* __restrict__ xred4,
                                                   const float4* __restrict__ affine,
                                                   const int* __restrict__ fun_ids,
                                                   float* __restrict__ y,
                                                   float4* __restrict__ post4) {
    const int tid = threadIdx.x;
    const int oo  = tid >> 5;                 // 0..7 : o-row within block
    const int il  = tid & 31;                 // i-quad index (i = 4*il .. 4*il+3)
    const int o   = blockIdx.x * OGROUP + oo;

    // ---- hoist per-element affine + fun_id-derived state (b-invariant) ----
    float4 A[4]; int f[4];
    #pragma unroll
    for (int j = 0; j < 4; ++j) {
        A[j] = affine[(size_t)o * 128 + il * 4 + j];
        f[j] = fun_ids[(size_t)o * 128 + il * 4 + j];
    }

    bool m1[4], m2[4], m3[4], m7[4], m8[4], me[4];
    float k1[4], k2[4], An[4], Bn[4], Dd[4];
    #pragma unroll
    for (int j = 0; j < 4; ++j) {
        const int fj = f[j];
        m1[j] = (fj == 1); m2[j] = (fj == 2); m3[j] = (fj == 3);
        m7[j] = (fj == 7); m8[j] = (fj == 8);
        me[j] = (fj >= 4 && fj <= 6) || (fj == 9);
        float k1v = 0.f, k2v = 0.f, Anv = 0.f, Bnv = 1.f, Ddv = 0.f;
        if      (fj == 4) { k1v = -2.f; Anv = 1.f; Bnv = -1.f; Ddv = 1.f; }  // tanh
        else if (fj == 5) { k1v = -1.f; Anv = 1.f; Bnv =  0.f; Ddv = 1.f; }  // sigmoid
        else if (fj == 6) { k2v = -1.f; }                                    // exp(-z^2)
        else if (fj == 9) { k1v =  1.f; }                                    // exp(z)
        k1[j] = k1v; k2[j] = k2v; An[j] = Anv; Bn[j] = Bnv; Dd[j] = Ddv;
    }

    const int b0 = blockIdx.y * BCHUNK;

    for (int bb = 0; bb < BCHUNK; ++bb) {
        const int b = b0 + bb;
        const float4 xr = xred4[(size_t)b * 32 + il];
        const float xv[4] = {xr.x, xr.y, xr.z, xr.w};

        float p[4];
        #pragma unroll
        for (int j = 0; j < 4; ++j) {
            const float z  = fmaf(A[j].x, xv[j], A[j].y);
            const float zz = z * z;
            float pv = m1[j] ? zz : z;
            pv = m2[j] ? zz * z : pv;
            pv = m7[j] ? fabsf(z) : pv;
            const float s = __sinf(z);
            pv = m3[j] ? s : pv;
            const float arg = fminf(fmaf(k2[j], zz, k1[j] * z), 80.f);
            const float e   = __expf(arg);
            const float num = fmaf(Bn[j], e, An[j]);
            const float den = fmaf(Dd[j], e, 1.0f);
            const float r   = num * __builtin_amdgcn_rcpf(den);
            pv = me[j] ? r : pv;
            // atan: 5-term minimax (abs err ~2e-7)
            const float az  = fabsf(z);
            const bool  big = az > 1.0f;
            const float t   = big ? __builtin_amdgcn_rcpf(az) : az;
            const float t2  = t * t;
            float q = fmaf(t2, -0.01172120f, 0.05265332f);
            q = fmaf(t2, q, -0.11643287f);
            q = fmaf(t2, q,  0.19354346f);
            q = fmaf(t2, q, -0.33262347f);
            q = fmaf(t2, q,  0.99997726f);
            q = t * q;
            q = big ? 1.57079632679f - q : q;
            const float at = copysignf(q, z);
            pv = m8[j] ? at : pv;
            p[j] = fmaf(A[j].z, pv, A[j].w);
        }

        post4[((size_t)b * 128 + o) * 32 + il] = make_float4(p[0], p[1], p[2], p[3]);

        float s = (p[0] + p[1]) + (p[2] + p[3]);
        s += __shfl_xor(s, 1, 64);
        s += __shfl_xor(s, 2, 64);
        s += __shfl_xor(s, 4, 64);
        s += __shfl_xor(s, 8, 64);
        s += __shfl_xor(s, 16, 64);
        if (il == 0) y[(size_t)b * 128 + o] = s;
    }
}

extern "C" void kernel_launch(void* const* d_in, const int* in_sizes, int n_in,
                              void* d_out, int out_size, void* d_ws, size_t ws_size,
                              hipStream_t stream) {
    const float* x       = (const float*)d_in[0];   // (batch, 128)
    const float* affine  = (const float*)d_in[1];   // (128, 128, 4)
    const float* mask    = (const float*)d_in[2];   // (128, 128)
    const int*   fun_ids = (const int*)d_in[3];     // (128, 128)

    const int batch = in_sizes[0] / 128;            // 4096

    float* xred     = (float*)d_ws;                 // batch*128 floats (2 MB)
    float* y        = (float*)d_out;                // batch*128
    float* postacts = y + (size_t)batch * 128;      // batch*128*128

    xred_kernel<<<dim3(128 / XR_RT, batch / XR_BC), dim3(256), 0, stream>>>(x, mask, xred);

    kan_main<<<dim3(128 / OGROUP, batch / BCHUNK), dim3(256), 0, stream>>>(
        (const float4*)xred, (const float4*)affine, fun_ids, y, (float4*)postacts);
}